// Round 6
// baseline (638.471 us; speedup 1.0000x reference)
//
#include <hip/hip_runtime.h>

#define NN 100000
#define NE 1600000
#define EDGE_BLK 1563               // fused1 edge blocks, 1024 edges each
#define MM_BLK 3125                 // NN/32 gemm tiles
#define NBIN 392                    // node bins: bin = node>>8 (256 nodes/bin)
#define NSB 196                     // hist/scatter blocks, 8192 edges each
#define ESB 8192
#define TOTCNT (2*NBIN*NSB)         // 153,664 (dir-major: dst bins then src bins)
#define SCAN_BLKS 151               // ceil(TOTCNT/1024)
#define FIXSCALE 68719476736.0f     // 2^36
#define FIXINV   (1.0 / 68719476736.0)
#define MASK48   0xFFFFFFFFFFFFULL

// ---------------- shared GEMM tile body:  out[32 x 128] = x_tile @ W -------
// R5-proven: bounded 2x8 register tile, 0.31 LDS-dw/FMA, 24.7 KB LDS,
// launch_bounds(256,4) caps VGPR at 128 (R4's 4x8 spilled at 256 VGPR).
__device__ __forceinline__ void matmul_tile(const float* __restrict__ x,
                                            const float* __restrict__ W,
                                            float* __restrict__ out,
                                            int tile, int tid,
                                            float (*xs)[129], float (*Ws)[128])
{
    int rg = tid >> 4;              // 0..15: row group (2 rows)
    int cg = tid & 15;              // 0..15: cols cg*4..+3 and 64+cg*4..+3
    float acc[2][8];
#pragma unroll
    for (int i = 0; i < 2; i++)
#pragma unroll
        for (int j = 0; j < 8; j++) acc[i][j] = 0.f;

    // stage x tile [32][128] (NN % 32 == 0, no ragged tile)
#pragma unroll
    for (int i = 0; i < 4; i++) {
        int idx = tid + i * 256;
        int rr = idx >> 5;
        int c4 = (idx & 31) << 2;
        *(float4*)&xs[rr][c4] =
            *(const float4*)(x + (size_t)(tile * 32 + rr) * 128 + c4);
    }

#pragma unroll
    for (int kh = 0; kh < 8; kh++) {
        __syncthreads();
#pragma unroll
        for (int i = 0; i < 2; i++) {
            int idx = tid + i * 256;
            int kk = idx >> 5;              // 0..15
            int c4 = (idx & 31) << 2;
            *(float4*)&Ws[kk][c4] =
                *(const float4*)(W + (size_t)(kh * 16 + kk) * 128 + c4);
        }
        __syncthreads();
#pragma unroll
        for (int k = 0; k < 16; k++) {
            float xv0 = xs[rg * 2 + 0][kh * 16 + k];
            float xv1 = xs[rg * 2 + 1][kh * 16 + k];
            float4 wa = *(const float4*)&Ws[k][cg * 4];
            float4 wb = *(const float4*)&Ws[k][64 + cg * 4];
#define FMA8(i, xv) \
            acc[i][0] = fmaf(xv, wa.x, acc[i][0]); \
            acc[i][1] = fmaf(xv, wa.y, acc[i][1]); \
            acc[i][2] = fmaf(xv, wa.z, acc[i][2]); \
            acc[i][3] = fmaf(xv, wa.w, acc[i][3]); \
            acc[i][4] = fmaf(xv, wb.x, acc[i][4]); \
            acc[i][5] = fmaf(xv, wb.y, acc[i][5]); \
            acc[i][6] = fmaf(xv, wb.z, acc[i][6]); \
            acc[i][7] = fmaf(xv, wb.w, acc[i][7]);
            FMA8(0, xv0) FMA8(1, xv1)
#undef FMA8
        }
    }

#pragma unroll
    for (int i = 0; i < 2; i++) {
        float* op = out + (size_t)(tile * 32 + rg * 2 + i) * 128;
        *(float4*)(op + cg * 4) =
            make_float4(acc[i][0], acc[i][1], acc[i][2], acc[i][3]);
        *(float4*)(op + 64 + cg * 4) =
            make_float4(acc[i][4], acc[i][5], acc[i][6], acc[i][7]);
    }
}

// ---------------- kernel 1: edge weights (pure stream) + layer-1 GEMM ------
// No global atomics anywhere (R2: memory-side RMW pipe is untouchable).
__global__ __launch_bounds__(256, 4) void fused1_kernel(
        const float* __restrict__ ef,
        const float* __restrict__ W_ef,
        const float* __restrict__ b_ef,
        float* __restrict__ w_raw,
        const float* __restrict__ node_feats,
        const float* __restrict__ W1,
        float* __restrict__ t_buf)
{
    __shared__ float xs[32][129];     // +1 pad: conflict-free column reads
    __shared__ float Ws[16][128];     // 16-row K-chunk: 8 KB -> 6 blocks/CU
    int tid = threadIdx.x;

    if (blockIdx.x < EDGE_BLK) {
        int base = blockIdx.x * 1024 + tid;
#pragma unroll
        for (int q = 0; q < 4; q++) {
            int e = base + q * 256;
            if (e >= NE) continue;
            const float4* p = (const float4*)(ef + (size_t)e * 16);
            float acc = b_ef[0];
#pragma unroll
            for (int i = 0; i < 4; i++) {
                float4 v = p[i];
                acc += v.x * W_ef[i*4+0] + v.y * W_ef[i*4+1]
                     + v.z * W_ef[i*4+2] + v.w * W_ef[i*4+3];
            }
            w_raw[e] = acc;
        }
        return;
    }

    matmul_tile(node_feats, W1, t_buf, blockIdx.x - EDGE_BLK, tid, xs, Ws);
}

// ---------------- kernel H: per-block bin histograms (LDS, no globals) -----
// counts layout: flat f = (dir*NBIN + bin)*NSB + blk, dir0 = dst, dir1 = src.
__global__ __launch_bounds__(256) void hist_kernel(
        const int* __restrict__ src, const int* __restrict__ dst,
        unsigned* __restrict__ counts)
{
    __shared__ unsigned hc[2 * NBIN];
    int t = threadIdx.x;
    for (int i = t; i < 2 * NBIN; i += 256) hc[i] = 0;
    __syncthreads();
    int base = blockIdx.x * ESB;
    for (int i = t; i < ESB; i += 256) {
        int e = base + i;
        if (e < NE) {
            atomicAdd(&hc[dst[e] >> 8], 1u);
            atomicAdd(&hc[NBIN + (src[e] >> 8)], 1u);
        }
    }
    __syncthreads();
    for (int i = t; i < 2 * NBIN; i += 256)
        counts[(size_t)i * NSB + blockIdx.x] = hc[i];
}

// ---------------- kernels SA/SB/SC: 3-level exclusive scan of counts -------
__global__ __launch_bounds__(256) void scanA_kernel(unsigned* __restrict__ counts,
                                                    unsigned* __restrict__ blkS)
{
    __shared__ unsigned s[256];
    int t = threadIdx.x;
    size_t base = (size_t)blockIdx.x * 1024 + t * 4;
    unsigned v[4];
#pragma unroll
    for (int i = 0; i < 4; i++) {
        size_t idx = base + i;
        v[i] = (idx < TOTCNT) ? counts[idx] : 0;
    }
    unsigned tsum = v[0] + v[1] + v[2] + v[3];
    s[t] = tsum;
    __syncthreads();
    for (int o = 1; o < 256; o <<= 1) {
        unsigned u = (t >= o) ? s[t - o] : 0;
        __syncthreads();
        s[t] += u;
        __syncthreads();
    }
    unsigned run = s[t] - tsum;        // exclusive
    if (t == 255) blkS[blockIdx.x] = s[255];
#pragma unroll
    for (int i = 0; i < 4; i++) {
        size_t idx = base + i;
        if (idx < TOTCNT) counts[idx] = run;
        run += v[i];
    }
}

__global__ void scanB_kernel(unsigned* __restrict__ blkS)
{
    __shared__ unsigned s[256];
    int t = threadIdx.x;
    unsigned v = (t < SCAN_BLKS) ? blkS[t] : 0;
    s[t] = v;
    __syncthreads();
    for (int o = 1; o < 256; o <<= 1) {
        unsigned u = (t >= o) ? s[t - o] : 0;
        __syncthreads();
        s[t] += u;
        __syncthreads();
    }
    if (t < SCAN_BLKS) blkS[t] = s[t] - v;   // exclusive
}

__global__ __launch_bounds__(256) void scanC_kernel(unsigned* __restrict__ counts,
                                                    const unsigned* __restrict__ blkS)
{
    unsigned add = blkS[blockIdx.x];
    size_t base = (size_t)blockIdx.x * 1024 + threadIdx.x;
#pragma unroll
    for (int i = 0; i < 4; i++) {
        size_t idx = base + i * 256;
        if (idx < TOTCNT) counts[idx] += add;
    }
}

// ---------------- kernel SC2: scatter edges into binned record arrays ------
// LDS cursors (CU-local atomics). drec packed int2: (src | dstloc<<17, w);
// srec int2: (srcloc, w). 17 bits suffice for src < 131072.
__global__ __launch_bounds__(256) void scatter2_kernel(
        const int* __restrict__ src, const int* __restrict__ dst,
        const float* __restrict__ w_raw, const unsigned* __restrict__ offs,
        int2* __restrict__ drec, int2* __restrict__ srec)
{
    __shared__ unsigned cur[2 * NBIN];
    int t = threadIdx.x;
    for (int i = t; i < 2 * NBIN; i += 256)
        cur[i] = offs[(size_t)i * NSB + blockIdx.x];
    __syncthreads();
    int base = blockIdx.x * ESB;
    for (int i = t; i < ESB; i += 256) {
        int e = base + i;
        if (e >= NE) continue;
        int s = src[e], d = dst[e];
        int wbits = __float_as_int(w_raw[e]);
        unsigned p0 = atomicAdd(&cur[d >> 8], 1u);
        drec[p0] = make_int2(s | ((d & 255) << 17), wbits);
        unsigned p1 = atomicAdd(&cur[NBIN + (s >> 8)], 1u);
        srec[p1 - NE] = make_int2(s & 255, wbits);
    }
}

// ---------------- kernel S: src-bin pass -> fo (LDS packed count|fixsum) ---
__global__ __launch_bounds__(256) void srcbin_kernel(
        const int2* __restrict__ srec, const unsigned* __restrict__ offs,
        float* __restrict__ fo)
{
    __shared__ unsigned long long acc[256];
    int t = threadIdx.x, b = blockIdx.x;
    acc[t] = 0ULL;
    __syncthreads();
    size_t flat = (size_t)(NBIN + b) * NSB;
    unsigned start = offs[flat];
    unsigned end = (b == NBIN - 1) ? (unsigned)(2 * (size_t)NE) : offs[flat + NSB];
    for (unsigned i = start + t; i < end; i += 256) {
        int2 r = srec[i - NE];
        float w = __int_as_float(r.y);
        unsigned long long pk = (1ULL << 48) |
            (unsigned long long)(w * FIXSCALE);
        atomicAdd(&acc[r.x], pk);
    }
    __syncthreads();
    int n = b * 256 + t;
    if (n < NN) {
        unsigned long long po = acc[t];
        int dout = (int)(po >> 48);
        float wo = (float)((double)(po & MASK48) * FIXINV);
        float no = 1.0f / sqrtf((float)(dout > 1 ? dout : 1));
        fo[n] = (wo > 0.f) ? no / sqrtf(wo) : 0.f;
    }
}

// ---------------- kernel D: dst-bin pass -> fi, row_ptr, CSR ---------------
// Bin record base == CSR base (bins are contiguous node ranges), so row_ptr
// and CSR placement need only a 256-wide LDS scan — no global scan at all.
__global__ __launch_bounds__(256) void dstbin_kernel(
        const int2* __restrict__ drec, const unsigned* __restrict__ offs,
        const float* __restrict__ fo,
        int* __restrict__ row_ptr, int2* __restrict__ csr)
{
    __shared__ unsigned long long acc[256];
    __shared__ unsigned sc[256];
    __shared__ unsigned cur[256];
    __shared__ float fil[256];
    int t = threadIdx.x, b = blockIdx.x;
    acc[t] = 0ULL;
    __syncthreads();
    size_t flat = (size_t)b * NSB;
    unsigned start = offs[flat];
    unsigned end = offs[flat + NSB];   // dst bin 391's next = src bin 0 = NE
    for (unsigned i = start + t; i < end; i += 256) {
        int2 r = drec[i];
        float w = __int_as_float(r.y);
        unsigned long long pk = (1ULL << 48) |
            (unsigned long long)(w * FIXSCALE);
        atomicAdd(&acc[(unsigned)r.x >> 17], pk);
    }
    __syncthreads();
    unsigned cnt = (unsigned)(acc[t] >> 48);
    {
        float wi = (float)((double)(acc[t] & MASK48) * FIXINV);
        float ni = 1.0f / sqrtf((float)((int)cnt > 1 ? (int)cnt : 1));
        fil[t] = (wi > 0.f) ? ni / sqrtf(wi) : 0.f;
    }
    sc[t] = cnt;
    __syncthreads();
    for (int o = 1; o < 256; o <<= 1) {
        unsigned u = (t >= o) ? sc[t - o] : 0;
        __syncthreads();
        sc[t] += u;
        __syncthreads();
    }
    unsigned excl = sc[t] - cnt;
    int n = b * 256 + t;
    if (n < NN) {
        row_ptr[n] = (int)(start + excl);
        if (n == NN - 1) row_ptr[NN] = NE;
    }
    cur[t] = excl;
    __syncthreads();
    for (unsigned i = start + t; i < end; i += 256) {
        int2 r = drec[i];
        unsigned loc = (unsigned)r.x >> 17;
        int s = r.x & 0x1FFFF;
        unsigned slot = atomicAdd(&cur[loc], 1u);
        float wn = __int_as_float(r.y) * fo[s] * fil[loc];
        csr[start + slot] = make_int2(s, __float_as_int(wn));
    }
}

// ---------------- kernel 5: standalone pure GEMM (layer 2) -----------------
__global__ __launch_bounds__(256, 4) void matmul_kernel(
        const float* __restrict__ x,
        const float* __restrict__ W,
        float* __restrict__ out)
{
    __shared__ float xs[32][129];
    __shared__ float Ws[16][128];
    matmul_tile(x, W, out, blockIdx.x, threadIdx.x, xs, Ws);
}

// ---------------- kernel 6: CSR SpMM, wave per row, 2 edges per load -------
// R5 post-mortem: 111us with no pipe >50% -> miss-latency x in-flight-
// INSTRUCTION concurrency bound (819 MB of random 512-B gathers, one
// dwordx2 instr per edge). R6: lanes 0-31 take even edges, 32-63 odd;
// each lane loads float4, so ONE wave-load fetches TWO 512-B rows (1 KB)
// -> half the load and shfl instructions, 2x bytes per vmcnt slot.
// Combine halves once per row via shfl_xor(32).
template <bool RELU>
__global__ __launch_bounds__(256) void spmm_kernel(
        const float* __restrict__ t,
        const int* __restrict__ row_ptr,
        const int2* __restrict__ csr,
        const float* __restrict__ bias,
        float* __restrict__ out)
{
    int gtid = blockIdx.x * blockDim.x + threadIdx.x;
    int row = gtid >> 6;
    int lane = threadIdx.x & 63;
    if (row >= NN) return;
    int half = lane >> 5;          // 0: even edges, 1: odd edges
    int sub  = lane & 31;          // owns features sub*4 .. sub*4+3
    int start = row_ptr[row], end = row_ptr[row + 1];
    float a0 = 0.f, a1 = 0.f, a2 = 0.f, a3 = 0.f;
    const float* tl = t + sub * 4;
    for (int base = start; base < end; base += 64) {
        int idx = base + lane;
        int2 pr = (idx < end) ? csr[idx] : make_int2(0, 0);
        int cnt = end - base; if (cnt > 64) cnt = 64;
        int cnt16 = (cnt + 15) & ~15;
        for (int j = 0; j < cnt16; j += 16) {
#pragma unroll
            for (int u = 0; u < 8; u++) {
                int eidx = j + 2 * u + half;      // per-lane edge index
                int s = __shfl(pr.x, eidx);
                float w = __int_as_float(__shfl(pr.y, eidx));
                float4 hv = *(const float4*)(tl + ((size_t)s << 7));
                a0 = fmaf(w, hv.x, a0);
                a1 = fmaf(w, hv.y, a1);
                a2 = fmaf(w, hv.z, a2);
                a3 = fmaf(w, hv.w, a3);
            }
        }
    }
    a0 += __shfl_xor(a0, 32);
    a1 += __shfl_xor(a1, 32);
    a2 += __shfl_xor(a2, 32);
    a3 += __shfl_xor(a3, 32);
    if (half == 0) {
        const float4 bv = *(const float4*)(bias + sub * 4);
        float o0 = a0 + bv.x, o1 = a1 + bv.y, o2 = a2 + bv.z, o3 = a3 + bv.w;
        if (RELU) {
            o0 = o0 > 0.f ? o0 : 0.f; o1 = o1 > 0.f ? o1 : 0.f;
            o2 = o2 > 0.f ? o2 : 0.f; o3 = o3 > 0.f ? o3 : 0.f;
        }
        *(float4*)(out + ((size_t)row << 7) + sub * 4) =
            make_float4(o0, o1, o2, o3);
    }
}

// ---------------------------------------------------------------------------
extern "C" void kernel_launch(void* const* d_in, const int* in_sizes, int n_in,
                              void* d_out, int out_size, void* d_ws, size_t ws_size,
                              hipStream_t stream)
{
    const float* node_feats = (const float*)d_in[0];
    const float* edge_feats = (const float*)d_in[1];
    const float* W_ef       = (const float*)d_in[2];
    const float* b_ef       = (const float*)d_in[3];
    const float* W1         = (const float*)d_in[4];
    const float* b1         = (const float*)d_in[5];
    const float* W2         = (const float*)d_in[6];
    const float* b2         = (const float*)d_in[7];
    const int*   src        = (const int*)d_in[8];
    const int*   dst        = (const int*)d_in[9];
    float* out = (float*)d_out;

    char* ws = (char*)d_ws;
    size_t off = 0;
    auto alloc = [&](size_t bytes) {
        off = (off + 255) & ~(size_t)255;
        void* p = ws + off;
        off += bytes;
        return p;
    };

    float*    w_raw  = (float*)alloc((size_t)NE * 4);
    unsigned* counts = (unsigned*)alloc((size_t)TOTCNT * 4);
    unsigned* blkS   = (unsigned*)alloc((size_t)SCAN_BLKS * 4);
    int2*     drec   = (int2*)alloc((size_t)NE * 8);
    int2*     srec   = (int2*)alloc((size_t)NE * 8);
    float*    fo     = (float*)alloc((size_t)NN * 4);
    int*      row_ptr= (int*)alloc((size_t)(NN + 1) * 4);
    int2*     csr    = (int2*)alloc((size_t)NE * 8);
    float*    t_buf  = (float*)alloc((size_t)NN * 128 * 4);
    float*    h_buf  = (float*)alloc((size_t)NN * 128 * 4);

    // histogram + scan chain first (independent of w_raw)
    hist_kernel<<<NSB, 256, 0, stream>>>(src, dst, counts);
    scanA_kernel<<<SCAN_BLKS, 256, 0, stream>>>(counts, blkS);
    scanB_kernel<<<1, 256, 0, stream>>>(blkS);
    scanC_kernel<<<SCAN_BLKS, 256, 0, stream>>>(counts, blkS);

    // edge-weight stream + independent layer-1 GEMM in one dispatch
    fused1_kernel<<<EDGE_BLK + MM_BLK, 256, 0, stream>>>(
        edge_feats, W_ef, b_ef, w_raw, node_feats, W1, t_buf);

    scatter2_kernel<<<NSB, 256, 0, stream>>>(src, dst, w_raw, counts, drec, srec);

    srcbin_kernel<<<NBIN, 256, 0, stream>>>(srec, counts, fo);

    dstbin_kernel<<<NBIN, 256, 0, stream>>>(drec, counts, fo, row_ptr, csr);

    // layer 1 aggregate (+ReLU)
    spmm_kernel<true><<<25000, 256, 0, stream>>>(
        t_buf, row_ptr, csr, b1, h_buf);

    // layer 2: pure GEMM then aggregate
    matmul_kernel<<<MM_BLK, 256, 0, stream>>>(h_buf, W2, t_buf);
    spmm_kernel<false><<<25000, 256, 0, stream>>>(
        t_buf, row_ptr, csr, b2, out);
}

// Round 7
// 519.303 us; speedup vs baseline: 1.2295x; 1.2295x over previous
//
#include <hip/hip_runtime.h>
#include <hip/hip_fp16.h>

#define NN 100000
#define NE 1600000
#define EDGE_BLK 1563               // fused1 edge blocks, 1024 edges each
#define MM_BLK 3125                 // NN/32 gemm tiles
#define NBIN 392                    // node bins: bin = node>>8 (256 nodes/bin)
#define NSB 196                     // hist/scatter blocks, 8192 edges each
#define ESB 8192
#define TOTCNT (2*NBIN*NSB)         // 153,664 (dir-major: dst bins then src bins)
#define SCAN_BLKS 151               // ceil(TOTCNT/1024)
#define FIXSCALE 68719476736.0f     // 2^36
#define FIXINV   (1.0 / 68719476736.0)
#define MASK48   0xFFFFFFFFFFFFULL

// ---------------- shared GEMM tile body:  out[32 x 128] = x_tile @ W -------
// R5-proven: bounded 2x8 register tile, 0.31 LDS-dw/FMA, 24.7 KB LDS,
// launch_bounds(256,4) caps VGPR at 128 (R4's 4x8 spilled at 256 VGPR).
// HALF_OUT: the GEMM outputs feed only the random-gather SpMMs, which R6
// established are byte-bound — store them fp16 (RNE) to halve gather bytes.
template <bool HALF_OUT>
__device__ __forceinline__ void matmul_tile(const float* __restrict__ x,
                                            const float* __restrict__ W,
                                            void* __restrict__ out,
                                            int tile, int tid,
                                            float (*xs)[129], float (*Ws)[128])
{
    int rg = tid >> 4;              // 0..15: row group (2 rows)
    int cg = tid & 15;              // 0..15: cols cg*4..+3 and 64+cg*4..+3
    float acc[2][8];
#pragma unroll
    for (int i = 0; i < 2; i++)
#pragma unroll
        for (int j = 0; j < 8; j++) acc[i][j] = 0.f;

    // stage x tile [32][128] (NN % 32 == 0, no ragged tile)
#pragma unroll
    for (int i = 0; i < 4; i++) {
        int idx = tid + i * 256;
        int rr = idx >> 5;
        int c4 = (idx & 31) << 2;
        *(float4*)&xs[rr][c4] =
            *(const float4*)(x + (size_t)(tile * 32 + rr) * 128 + c4);
    }

#pragma unroll
    for (int kh = 0; kh < 8; kh++) {
        __syncthreads();
#pragma unroll
        for (int i = 0; i < 2; i++) {
            int idx = tid + i * 256;
            int kk = idx >> 5;              // 0..15
            int c4 = (idx & 31) << 2;
            *(float4*)&Ws[kk][c4] =
                *(const float4*)(W + (size_t)(kh * 16 + kk) * 128 + c4);
        }
        __syncthreads();
#pragma unroll
        for (int k = 0; k < 16; k++) {
            float xv0 = xs[rg * 2 + 0][kh * 16 + k];
            float xv1 = xs[rg * 2 + 1][kh * 16 + k];
            float4 wa = *(const float4*)&Ws[k][cg * 4];
            float4 wb = *(const float4*)&Ws[k][64 + cg * 4];
#define FMA8(i, xv) \
            acc[i][0] = fmaf(xv, wa.x, acc[i][0]); \
            acc[i][1] = fmaf(xv, wa.y, acc[i][1]); \
            acc[i][2] = fmaf(xv, wa.z, acc[i][2]); \
            acc[i][3] = fmaf(xv, wa.w, acc[i][3]); \
            acc[i][4] = fmaf(xv, wb.x, acc[i][4]); \
            acc[i][5] = fmaf(xv, wb.y, acc[i][5]); \
            acc[i][6] = fmaf(xv, wb.z, acc[i][6]); \
            acc[i][7] = fmaf(xv, wb.w, acc[i][7]);
            FMA8(0, xv0) FMA8(1, xv1)
#undef FMA8
        }
    }

    if (HALF_OUT) {
#pragma unroll
        for (int i = 0; i < 2; i++) {
            __half* op = (__half*)out + (size_t)(tile * 32 + rg * 2 + i) * 128;
            __half2 p0 = __floats2half2_rn(acc[i][0], acc[i][1]);
            __half2 p1 = __floats2half2_rn(acc[i][2], acc[i][3]);
            __half2 p2 = __floats2half2_rn(acc[i][4], acc[i][5]);
            __half2 p3 = __floats2half2_rn(acc[i][6], acc[i][7]);
            uint2 va, vb;
            va.x = *(unsigned*)&p0; va.y = *(unsigned*)&p1;
            vb.x = *(unsigned*)&p2; vb.y = *(unsigned*)&p3;
            *(uint2*)(op + cg * 4) = va;
            *(uint2*)(op + 64 + cg * 4) = vb;
        }
    } else {
#pragma unroll
        for (int i = 0; i < 2; i++) {
            float* op = (float*)out + (size_t)(tile * 32 + rg * 2 + i) * 128;
            *(float4*)(op + cg * 4) =
                make_float4(acc[i][0], acc[i][1], acc[i][2], acc[i][3]);
            *(float4*)(op + 64 + cg * 4) =
                make_float4(acc[i][4], acc[i][5], acc[i][6], acc[i][7]);
        }
    }
}

// ---------------- kernel 1: edge weights (pure stream) + layer-1 GEMM ------
// No global atomics anywhere (R2: memory-side RMW pipe is untouchable).
__global__ __launch_bounds__(256, 4) void fused1_kernel(
        const float* __restrict__ ef,
        const float* __restrict__ W_ef,
        const float* __restrict__ b_ef,
        float* __restrict__ w_raw,
        const float* __restrict__ node_feats,
        const float* __restrict__ W1,
        __half* __restrict__ t_buf)
{
    __shared__ float xs[32][129];     // +1 pad: conflict-free column reads
    __shared__ float Ws[16][128];     // 16-row K-chunk: 8 KB -> 6 blocks/CU
    int tid = threadIdx.x;

    if (blockIdx.x < EDGE_BLK) {
        int base = blockIdx.x * 1024 + tid;
#pragma unroll
        for (int q = 0; q < 4; q++) {
            int e = base + q * 256;
            if (e >= NE) continue;
            const float4* p = (const float4*)(ef + (size_t)e * 16);
            float acc = b_ef[0];
#pragma unroll
            for (int i = 0; i < 4; i++) {
                float4 v = p[i];
                acc += v.x * W_ef[i*4+0] + v.y * W_ef[i*4+1]
                     + v.z * W_ef[i*4+2] + v.w * W_ef[i*4+3];
            }
            w_raw[e] = acc;
        }
        return;
    }

    matmul_tile<true>(node_feats, W1, t_buf, blockIdx.x - EDGE_BLK, tid, xs, Ws);
}

// ---------------- kernel H: per-block bin histograms (LDS, no globals) -----
// counts layout: flat f = (dir*NBIN + bin)*NSB + blk, dir0 = dst, dir1 = src.
__global__ __launch_bounds__(256) void hist_kernel(
        const int* __restrict__ src, const int* __restrict__ dst,
        unsigned* __restrict__ counts)
{
    __shared__ unsigned hc[2 * NBIN];
    int t = threadIdx.x;
    for (int i = t; i < 2 * NBIN; i += 256) hc[i] = 0;
    __syncthreads();
    int base = blockIdx.x * ESB;
    for (int i = t; i < ESB; i += 256) {
        int e = base + i;
        if (e < NE) {
            atomicAdd(&hc[dst[e] >> 8], 1u);
            atomicAdd(&hc[NBIN + (src[e] >> 8)], 1u);
        }
    }
    __syncthreads();
    for (int i = t; i < 2 * NBIN; i += 256)
        counts[(size_t)i * NSB + blockIdx.x] = hc[i];
}

// ---------------- kernels SA/SB/SC: 3-level exclusive scan of counts -------
__global__ __launch_bounds__(256) void scanA_kernel(unsigned* __restrict__ counts,
                                                    unsigned* __restrict__ blkS)
{
    __shared__ unsigned s[256];
    int t = threadIdx.x;
    size_t base = (size_t)blockIdx.x * 1024 + t * 4;
    unsigned v[4];
#pragma unroll
    for (int i = 0; i < 4; i++) {
        size_t idx = base + i;
        v[i] = (idx < TOTCNT) ? counts[idx] : 0;
    }
    unsigned tsum = v[0] + v[1] + v[2] + v[3];
    s[t] = tsum;
    __syncthreads();
    for (int o = 1; o < 256; o <<= 1) {
        unsigned u = (t >= o) ? s[t - o] : 0;
        __syncthreads();
        s[t] += u;
        __syncthreads();
    }
    unsigned run = s[t] - tsum;        // exclusive
    if (t == 255) blkS[blockIdx.x] = s[255];
#pragma unroll
    for (int i = 0; i < 4; i++) {
        size_t idx = base + i;
        if (idx < TOTCNT) counts[idx] = run;
        run += v[i];
    }
}

__global__ void scanB_kernel(unsigned* __restrict__ blkS)
{
    __shared__ unsigned s[256];
    int t = threadIdx.x;
    unsigned v = (t < SCAN_BLKS) ? blkS[t] : 0;
    s[t] = v;
    __syncthreads();
    for (int o = 1; o < 256; o <<= 1) {
        unsigned u = (t >= o) ? s[t - o] : 0;
        __syncthreads();
        s[t] += u;
        __syncthreads();
    }
    if (t < SCAN_BLKS) blkS[t] = s[t] - v;   // exclusive
}

__global__ __launch_bounds__(256) void scanC_kernel(unsigned* __restrict__ counts,
                                                    const unsigned* __restrict__ blkS)
{
    unsigned add = blkS[blockIdx.x];
    size_t base = (size_t)blockIdx.x * 1024 + threadIdx.x;
#pragma unroll
    for (int i = 0; i < 4; i++) {
        size_t idx = base + i * 256;
        if (idx < TOTCNT) counts[idx] += add;
    }
}

// ---------------- kernel SC2: scatter edges into binned record arrays ------
// LDS cursors (CU-local atomics). drec packed int2: (src | dstloc<<17, w);
// srec int2: (srcloc, w). 17 bits suffice for src < 131072.
__global__ __launch_bounds__(256) void scatter2_kernel(
        const int* __restrict__ src, const int* __restrict__ dst,
        const float* __restrict__ w_raw, const unsigned* __restrict__ offs,
        int2* __restrict__ drec, int2* __restrict__ srec)
{
    __shared__ unsigned cur[2 * NBIN];
    int t = threadIdx.x;
    for (int i = t; i < 2 * NBIN; i += 256)
        cur[i] = offs[(size_t)i * NSB + blockIdx.x];
    __syncthreads();
    int base = blockIdx.x * ESB;
    for (int i = t; i < ESB; i += 256) {
        int e = base + i;
        if (e >= NE) continue;
        int s = src[e], d = dst[e];
        int wbits = __float_as_int(w_raw[e]);
        unsigned p0 = atomicAdd(&cur[d >> 8], 1u);
        drec[p0] = make_int2(s | ((d & 255) << 17), wbits);
        unsigned p1 = atomicAdd(&cur[NBIN + (s >> 8)], 1u);
        srec[p1 - NE] = make_int2(s & 255, wbits);
    }
}

// ---------------- kernel S: src-bin pass -> fo (LDS packed count|fixsum) ---
__global__ __launch_bounds__(256) void srcbin_kernel(
        const int2* __restrict__ srec, const unsigned* __restrict__ offs,
        float* __restrict__ fo)
{
    __shared__ unsigned long long acc[256];
    int t = threadIdx.x, b = blockIdx.x;
    acc[t] = 0ULL;
    __syncthreads();
    size_t flat = (size_t)(NBIN + b) * NSB;
    unsigned start = offs[flat];
    unsigned end = (b == NBIN - 1) ? (unsigned)(2 * (size_t)NE) : offs[flat + NSB];
    for (unsigned i = start + t; i < end; i += 256) {
        int2 r = srec[i - NE];
        float w = __int_as_float(r.y);
        unsigned long long pk = (1ULL << 48) |
            (unsigned long long)(w * FIXSCALE);
        atomicAdd(&acc[r.x], pk);
    }
    __syncthreads();
    int n = b * 256 + t;
    if (n < NN) {
        unsigned long long po = acc[t];
        int dout = (int)(po >> 48);
        float wo = (float)((double)(po & MASK48) * FIXINV);
        float no = 1.0f / sqrtf((float)(dout > 1 ? dout : 1));
        fo[n] = (wo > 0.f) ? no / sqrtf(wo) : 0.f;
    }
}

// ---------------- kernel D: dst-bin pass -> fi, row_ptr, CSR ---------------
// Bin record base == CSR base (bins are contiguous node ranges), so row_ptr
// and CSR placement need only a 256-wide LDS scan — no global scan at all.
__global__ __launch_bounds__(256) void dstbin_kernel(
        const int2* __restrict__ drec, const unsigned* __restrict__ offs,
        const float* __restrict__ fo,
        int* __restrict__ row_ptr, int2* __restrict__ csr)
{
    __shared__ unsigned long long acc[256];
    __shared__ unsigned sc[256];
    __shared__ unsigned cur[256];
    __shared__ float fil[256];
    int t = threadIdx.x, b = blockIdx.x;
    acc[t] = 0ULL;
    __syncthreads();
    size_t flat = (size_t)b * NSB;
    unsigned start = offs[flat];
    unsigned end = offs[flat + NSB];   // dst bin 391's next = src bin 0 = NE
    for (unsigned i = start + t; i < end; i += 256) {
        int2 r = drec[i];
        float w = __int_as_float(r.y);
        unsigned long long pk = (1ULL << 48) |
            (unsigned long long)(w * FIXSCALE);
        atomicAdd(&acc[(unsigned)r.x >> 17], pk);
    }
    __syncthreads();
    unsigned cnt = (unsigned)(acc[t] >> 48);
    {
        float wi = (float)((double)(acc[t] & MASK48) * FIXINV);
        float ni = 1.0f / sqrtf((float)((int)cnt > 1 ? (int)cnt : 1));
        fil[t] = (wi > 0.f) ? ni / sqrtf(wi) : 0.f;
    }
    sc[t] = cnt;
    __syncthreads();
    for (int o = 1; o < 256; o <<= 1) {
        unsigned u = (t >= o) ? sc[t - o] : 0;
        __syncthreads();
        sc[t] += u;
        __syncthreads();
    }
    unsigned excl = sc[t] - cnt;
    int n = b * 256 + t;
    if (n < NN) {
        row_ptr[n] = (int)(start + excl);
        if (n == NN - 1) row_ptr[NN] = NE;
    }
    cur[t] = excl;
    __syncthreads();
    for (unsigned i = start + t; i < end; i += 256) {
        int2 r = drec[i];
        unsigned loc = (unsigned)r.x >> 17;
        int s = r.x & 0x1FFFF;
        unsigned slot = atomicAdd(&cur[loc], 1u);
        float wn = __int_as_float(r.y) * fo[s] * fil[loc];
        csr[start + slot] = make_int2(s, __float_as_int(wn));
    }
}

// ---------------- kernel 5: standalone pure GEMM (layer 2) -----------------
__global__ __launch_bounds__(256, 4) void matmul_kernel(
        const float* __restrict__ x,
        const float* __restrict__ W,
        __half* __restrict__ out)
{
    __shared__ float xs[32][129];
    __shared__ float Ws[16][128];
    matmul_tile<true>(x, W, out, blockIdx.x, threadIdx.x, xs, Ws);
}

// ---------------- kernel 6: CSR SpMM, wave per row (R5 structure) ----------
// R6 post-mortem: instruction-count halving was null; R1/R6 exclude wave-
// count and instr-slot limits -> the gather is BYTE/line-fill bound (380 MB
// FETCH pinned, ~3.85 TB/s in every variant). R7: gather rows are fp16
// (halves bytes and 128B-lines per row); accumulate fp32.
template <bool RELU>
__global__ __launch_bounds__(256) void spmm_kernel(
        const __half* __restrict__ t,
        const int* __restrict__ row_ptr,
        const int2* __restrict__ csr,
        const float* __restrict__ bias,
        float* __restrict__ out)
{
    int gtid = blockIdx.x * blockDim.x + threadIdx.x;
    int row = gtid >> 6;
    int lane = threadIdx.x & 63;
    if (row >= NN) return;
    int start = row_ptr[row], end = row_ptr[row + 1];
    float ax = 0.f, ay = 0.f;
    const __half* tl = t + lane * 2;
    for (int base = start; base < end; base += 64) {
        int idx = base + lane;
        int2 pr = (idx < end) ? csr[idx] : make_int2(0, 0);
        int cnt = end - base; if (cnt > 64) cnt = 64;
        int cnt8 = (cnt + 7) & ~7;
        for (int j = 0; j < cnt8; j += 8) {
#pragma unroll
            for (int u = 0; u < 8; u++) {
                int s = __shfl(pr.x, j + u);
                float w = __int_as_float(__shfl(pr.y, j + u));
                __half2 hv = *(const __half2*)(tl + ((size_t)s << 7));
                float2 f = __half22float2(hv);
                ax = fmaf(w, f.x, ax);
                ay = fmaf(w, f.y, ay);
            }
        }
    }
    float ox = ax + bias[lane * 2];
    float oy = ay + bias[lane * 2 + 1];
    if (RELU) { ox = ox > 0.f ? ox : 0.f; oy = oy > 0.f ? oy : 0.f; }
    *(float2*)(out + ((size_t)row << 7) + lane * 2) = make_float2(ox, oy);
}

// ---------------------------------------------------------------------------
extern "C" void kernel_launch(void* const* d_in, const int* in_sizes, int n_in,
                              void* d_out, int out_size, void* d_ws, size_t ws_size,
                              hipStream_t stream)
{
    const float* node_feats = (const float*)d_in[0];
    const float* edge_feats = (const float*)d_in[1];
    const float* W_ef       = (const float*)d_in[2];
    const float* b_ef       = (const float*)d_in[3];
    const float* W1         = (const float*)d_in[4];
    const float* b1         = (const float*)d_in[5];
    const float* W2         = (const float*)d_in[6];
    const float* b2         = (const float*)d_in[7];
    const int*   src        = (const int*)d_in[8];
    const int*   dst        = (const int*)d_in[9];
    float* out = (float*)d_out;

    char* ws = (char*)d_ws;
    size_t off = 0;
    auto alloc = [&](size_t bytes) {
        off = (off + 255) & ~(size_t)255;
        void* p = ws + off;
        off += bytes;
        return p;
    };

    float*    w_raw  = (float*)alloc((size_t)NE * 4);
    unsigned* counts = (unsigned*)alloc((size_t)TOTCNT * 4);
    unsigned* blkS   = (unsigned*)alloc((size_t)SCAN_BLKS * 4);
    int2*     drec   = (int2*)alloc((size_t)NE * 8);
    int2*     srec   = (int2*)alloc((size_t)NE * 8);
    float*    fo     = (float*)alloc((size_t)NN * 4);
    int*      row_ptr= (int*)alloc((size_t)(NN + 1) * 4);
    int2*     csr    = (int2*)alloc((size_t)NE * 8);
    __half*   t_buf  = (__half*)alloc((size_t)NN * 128 * 2);
    float*    h_buf  = (float*)alloc((size_t)NN * 128 * 4);

    // histogram + scan chain first (independent of w_raw)
    hist_kernel<<<NSB, 256, 0, stream>>>(src, dst, counts);
    scanA_kernel<<<SCAN_BLKS, 256, 0, stream>>>(counts, blkS);
    scanB_kernel<<<1, 256, 0, stream>>>(blkS);
    scanC_kernel<<<SCAN_BLKS, 256, 0, stream>>>(counts, blkS);

    // edge-weight stream + independent layer-1 GEMM in one dispatch
    fused1_kernel<<<EDGE_BLK + MM_BLK, 256, 0, stream>>>(
        edge_feats, W_ef, b_ef, w_raw, node_feats, W1, t_buf);

    scatter2_kernel<<<NSB, 256, 0, stream>>>(src, dst, w_raw, counts, drec, srec);

    srcbin_kernel<<<NBIN, 256, 0, stream>>>(srec, counts, fo);

    dstbin_kernel<<<NBIN, 256, 0, stream>>>(drec, counts, fo, row_ptr, csr);

    // layer 1 aggregate (+ReLU)
    spmm_kernel<true><<<25000, 256, 0, stream>>>(
        t_buf, row_ptr, csr, b1, h_buf);

    // layer 2: pure GEMM then aggregate
    matmul_kernel<<<MM_BLK, 256, 0, stream>>>(h_buf, W2, t_buf);
    spmm_kernel<false><<<25000, 256, 0, stream>>>(
        t_buf, row_ptr, csr, b2, out);
}